// Round 1
// baseline (9071.446 us; speedup 1.0000x reference)
//
#include <hip/hip_runtime.h>
#include <cstdint>
#include <cstddef>

// CustomLSTM: B=64, S=512, I=1024, H=1024.
// Plan:
//   K1: convert W fp32 -> bf16, swizzled into MFMA-B-fragment order.
//   K2: xW = x@W + bias  (bf16 MFMA, 128x128 tiles), stored bf16 in scan layout.
//   K3: persistent scan: 256 wgs (4 batch-groups x 64 unit-groups), U held in
//       VGPRs as B-fragments, h exchanged via global bf16 double-buffer +
//       per-group device-scope barrier each step. c stays in registers.

typedef __attribute__((ext_vector_type(4))) float        f32x4;
typedef __attribute__((ext_vector_type(8))) short        s16x8;
typedef __attribute__((ext_vector_type(4))) unsigned int u32x4;

#define S_LEN 512
#define HID   33554432   // 64*512*1024

__device__ __forceinline__ unsigned short f2bf(float f) {
  unsigned u = __builtin_bit_cast(unsigned, f);
  u += 0x7FFFu + ((u >> 16) & 1u);           // round-to-nearest-even
  return (unsigned short)(u >> 16);
}
__device__ __forceinline__ float bf2f(unsigned short h) {
  unsigned u = ((unsigned)h) << 16;
  return __builtin_bit_cast(float, u);
}
__device__ __forceinline__ float sigm(float x) {
  return __fdividef(1.f, 1.f + __expf(-x));
}
__device__ __forceinline__ float tanh_(float x) {
  // stable both directions: exp overflow -> inf -> term -> 0
  return 1.f - __fdividef(2.f, 1.f + __expf(2.f * x));
}

// ---------------- K1: W fp32 -> bf16, B-fragment swizzle ----------------
// W_sw layout: [kb=K/32][nb=N/128][ksub=4][col=128][i=8]  (k = kb*32+ksub*8+i)
__global__ __launch_bounds__(256) void k_convW(const float* __restrict__ W,
                                               unsigned short* __restrict__ Wsw) {
  int idx = blockIdx.x * 256 + threadIdx.x;   // 0 .. 4194303
  int k = idx >> 12, c = idx & 4095;
  int kb = k >> 5, ksub = (k >> 3) & 3, i = k & 7;
  int nb = c >> 7, col = c & 127;
  Wsw[(size_t)(((kb * 32 + nb) * 4 + ksub) * 128 + col) * 8 + i] = f2bf(W[idx]);
}

// ---------------- K2: xW = x @ W + bias ----------------
// grid (nb=32, mb=256), 256 thr. Output layout: xW[g][s][b][j] bf16,
// offset = ((g*512+s)*64+b)*1024 + j   (g=gate 0..3, j=0..1023)
__global__ __launch_bounds__(256) void k_gemm(const float* __restrict__ x,
                                              const unsigned short* __restrict__ Wsw,
                                              const float* __restrict__ bias,
                                              unsigned short* __restrict__ xW) {
  __shared__ __align__(16) short As[4096];   // [ksub=4][row=128][8] bf16
  __shared__ __align__(16) short Bs[4096];   // [ksub=4][col=128][8] bf16
  const int nb = blockIdx.x;
  const int mb = blockIdx.y;
  const int tid = threadIdx.x;
  const int w = tid >> 6, lane = tid & 63;
  const int wm = w >> 1, wn = w & 1;
  const int quad = lane >> 4, l15 = lane & 15;

  f32x4 acc[4][4];
#pragma unroll
  for (int mt = 0; mt < 4; ++mt)
#pragma unroll
    for (int nt = 0; nt < 4; ++nt) acc[mt][nt] = (f32x4){0.f, 0.f, 0.f, 0.f};

  const int r = tid >> 1, half = tid & 1;
  const float* xrow = x + (size_t)(mb * 128 + r) * 1024 + half * 16;
  const u32x4* wsrc = (const u32x4*)Wsw;
  u32x4* bdst = (u32x4*)Bs;
  s16x8* asv = (s16x8*)As;

  for (int kb = 0; kb < 32; ++kb) {
    // stage A: 16 consecutive k per thread, fp32 -> bf16
    f32x4 v0 = *(const f32x4*)(xrow + kb * 32);
    f32x4 v1 = *(const f32x4*)(xrow + kb * 32 + 4);
    f32x4 v2 = *(const f32x4*)(xrow + kb * 32 + 8);
    f32x4 v3 = *(const f32x4*)(xrow + kb * 32 + 12);
    s16x8 s0, s1;
    s0[0] = (short)f2bf(v0[0]); s0[1] = (short)f2bf(v0[1]);
    s0[2] = (short)f2bf(v0[2]); s0[3] = (short)f2bf(v0[3]);
    s0[4] = (short)f2bf(v1[0]); s0[5] = (short)f2bf(v1[1]);
    s0[6] = (short)f2bf(v1[2]); s0[7] = (short)f2bf(v1[3]);
    s1[0] = (short)f2bf(v2[0]); s1[1] = (short)f2bf(v2[1]);
    s1[2] = (short)f2bf(v2[2]); s1[3] = (short)f2bf(v2[3]);
    s1[4] = (short)f2bf(v3[0]); s1[5] = (short)f2bf(v3[1]);
    s1[6] = (short)f2bf(v3[2]); s1[7] = (short)f2bf(v3[3]);
    asv[(half * 2 + 0) * 128 + r] = s0;
    asv[(half * 2 + 1) * 128 + r] = s1;
    // stage B: contiguous 8KB block copy (already fragment order)
    const u32x4* bsrc = wsrc + (size_t)(kb * 32 + nb) * 512;
    bdst[tid] = bsrc[tid];
    bdst[tid + 256] = bsrc[tid + 256];
    __syncthreads();

    s16x8 a[4], b[4];
#pragma unroll
    for (int mt = 0; mt < 4; ++mt)
      a[mt] = ((const s16x8*)As)[quad * 128 + wm * 64 + mt * 16 + l15];
#pragma unroll
    for (int nt = 0; nt < 4; ++nt)
      b[nt] = ((const s16x8*)Bs)[quad * 128 + wn * 64 + nt * 16 + l15];
#pragma unroll
    for (int mt = 0; mt < 4; ++mt)
#pragma unroll
      for (int nt = 0; nt < 4; ++nt)
        acc[mt][nt] =
            __builtin_amdgcn_mfma_f32_16x16x32_bf16(a[mt], b[nt], acc[mt][nt], 0, 0, 0);
    __syncthreads();
  }

  // epilogue: + bias, write bf16 into scan layout
#pragma unroll
  for (int mt = 0; mt < 4; ++mt) {
    const int gr0 = mb * 128 + wm * 64 + mt * 16 + quad * 4;
#pragma unroll
    for (int nt = 0; nt < 4; ++nt) {
      const int gc = nb * 128 + wn * 64 + nt * 16 + l15;
      const int g = gc >> 10, jg = gc & 1023;
      const float bb = bias[gc];
#pragma unroll
      for (int r2 = 0; r2 < 4; ++r2) {
        const int gr = gr0 + r2;
        const int bi = gr >> 9, s = gr & 511;   // row = b*512 + s
        xW[(size_t)((g * 512 + s) * 64 + bi) * 1024 + jg] = f2bf(acc[mt][nt][r2] + bb);
      }
    }
  }
}

// ---------------- K3: persistent scan ----------------
// 256 wgs x 256 thr. wg: mi=wg>>6 (batch group of 16), ni=wg&63 (16 units).
// wave w = K-slice [w*256, w*256+256). U B-frags live in 128 VGPRs/lane.
// h_buf (global, bf16, double-buffered): [parity][mi][kb=32][lane=64][8],
// exactly A-fragment order so staging is a linear 32KB copy.
__global__ __launch_bounds__(256, 1) void k_scan(const float* __restrict__ U,
                                                 const unsigned short* __restrict__ xW,
                                                 unsigned short* hbuf,
                                                 unsigned* bar,
                                                 float* __restrict__ out) {
  __shared__ __align__(16) short hA[16384];   // 32KB staged h tile
  __shared__ __align__(16) float P[5120];     // [w=4][g=4][j=16][b=20pad] partials
  __shared__ char pad[32768];                 // force 1 wg/CU (84KB total LDS)

  const int wg = blockIdx.x;
  const int mi = wg >> 6, ni = wg & 63;
  const int tid = threadIdx.x;
  const int w = tid >> 6, lane = tid & 63;
  const int quad = lane >> 4, l15 = lane & 15;
  const int b_loc = tid >> 4, j_loc = tid & 15;
  if (((size_t)out & 2) != 0) pad[tid] = 0;   // never true; keeps pad alive

  // ---- load U fragments into registers (one-time) ----
  s16x8 uf[4][8];
  {
    const int cbase = ni * 16 + l15;
#pragma unroll
    for (int g = 0; g < 4; ++g) {
      const float* Ucol = U + (size_t)(g * 1024) * 4096 + cbase;
      // note: U row index = k (0..1023), row stride 4096
#pragma unroll
      for (int kb = 0; kb < 8; ++kb) {
        const int k0 = w * 256 + kb * 32 + quad * 8;
        s16x8 v;
#pragma unroll
        for (int i = 0; i < 8; ++i)
          v[i] = (short)f2bf(U[(size_t)(k0 + i) * 4096 + g * 1024 + cbase]);
        uf[g][kb] = v;
        (void)Ucol;
      }
    }
  }

  unsigned* barp = bar + mi * 32;             // 128B-separated counters
  const int bg = mi * 16 + b_loc;             // global batch
  const int jg = ni * 16 + j_loc;             // global hidden unit
  const size_t hb_w_off =
      (size_t)((mi * 32 + (jg >> 5)) * 64 + ((jg >> 3) & 3) * 16 + b_loc) * 8 + (jg & 7);
  float c = 0.f;
  const s16x8* hAv = (const s16x8*)hA;

  for (int t = 0; t < S_LEN; ++t) {
    // prefetch xW for this (t, b, j): 4 gates
    unsigned short xwv[4];
#pragma unroll
    for (int g = 0; g < 4; ++g)
      xwv[g] = xW[(size_t)((g * 512 + t) * 64 + bg) * 1024 + jg];

    float gate[4];
    if (t > 0) {
      if (tid == 0) {
        while (__hip_atomic_load(barp, __ATOMIC_RELAXED, __HIP_MEMORY_SCOPE_AGENT) <
               (unsigned)(t * 64))
          __builtin_amdgcn_s_sleep(1);
        __threadfence();   // acquire: invalidate stale L1/L2 before reading h
      }
      __syncthreads();
      // stage h tile (32KB linear copy, fragment order)
      const u32x4* src =
          (const u32x4*)(hbuf + (size_t)((t & 1) ^ 1) * 65536 + (size_t)mi * 16384);
      u32x4* dst = (u32x4*)hA;
#pragma unroll
      for (int c2 = 0; c2 < 8; ++c2) dst[c2 * 256 + tid] = src[c2 * 256 + tid];
      __syncthreads();

      f32x4 acc[4];
#pragma unroll
      for (int g = 0; g < 4; ++g) acc[g] = (f32x4){0.f, 0.f, 0.f, 0.f};
#pragma unroll
      for (int kb = 0; kb < 8; ++kb) {
        s16x8 a = hAv[(w * 8 + kb) * 64 + lane];
#pragma unroll
        for (int g = 0; g < 4; ++g)
          acc[g] = __builtin_amdgcn_mfma_f32_16x16x32_bf16(a, uf[g][kb], acc[g], 0, 0, 0);
      }
      // write partial sums: P[((w*4+g)*16 + j)*20 + b0..b0+3]
#pragma unroll
      for (int g = 0; g < 4; ++g) {
        float* dp = &P[(((w * 4 + g) * 16) + l15) * 20 + quad * 4];
        *(f32x4*)dp = acc[g];
      }
      __syncthreads();
#pragma unroll
      for (int g = 0; g < 4; ++g) {
        float s = bf2f(xwv[g]);
#pragma unroll
        for (int w2 = 0; w2 < 4; ++w2)
          s += P[((w2 * 4 + g) * 16 + j_loc) * 20 + b_loc];
        gate[g] = s;
      }
    } else {
      // h0 = 0: gates are xW only
#pragma unroll
      for (int g = 0; g < 4; ++g) gate[g] = bf2f(xwv[g]);
    }

    const float it = sigm(gate[0]);
    const float ft = sigm(gate[1]);
    const float gt = tanh_(gate[2]);
    const float ot = sigm(gate[3]);
    c = ft * c + it * gt;
    const float h = ot * tanh_(c);

    out[(size_t)bg * (S_LEN * 1024) + (size_t)t * 1024 + jg] = h;
    hbuf[(size_t)(t & 1) * 65536 + hb_w_off] = f2bf(h);
    if (t == S_LEN - 1) {
      out[HID + (size_t)bg * 1024 + jg] = h;                 // h_t
      out[HID + 65536 + (size_t)bg * 1024 + jg] = c;         // c_t
    }

    __syncthreads();   // all waves' global stores drained (vmcnt before barrier)
    if (tid == 0) {
      __threadfence();                 // release: write back L2 to LLC
      atomicAdd(barp, 1u);             // device-scope arrival
    }
  }
}

// ---------------- launch ----------------
extern "C" void kernel_launch(void* const* d_in, const int* in_sizes, int n_in,
                              void* d_out, int out_size, void* d_ws, size_t ws_size,
                              hipStream_t stream) {
  const float* x = (const float*)d_in[0];     // [64,512,1024]
  const float* W = (const float*)d_in[1];     // [1024,4096]
  const float* U = (const float*)d_in[2];     // [1024,4096]
  const float* bias = (const float*)d_in[3];  // [4096]
  float* out = (float*)d_out;
  char* ws = (char*)d_ws;

  // ws layout (needs ~264.2 MiB):
  unsigned* bar = (unsigned*)ws;                                    // 1 KB
  unsigned short* hbuf = (unsigned short*)(ws + 1024);              // 256 KB
  unsigned short* Wsw = (unsigned short*)(ws + 1024 + 262144);      // 8 MB
  unsigned short* xW = (unsigned short*)(ws + 1024 + 262144 + 8388608);  // 256 MB

  hipMemsetAsync(ws, 0, 1024, stream);   // zero barrier counters

  hipLaunchKernelGGL(k_convW, dim3(16384), dim3(256), 0, stream, W, Wsw);
  hipLaunchKernelGGL(k_gemm, dim3(32, 256), dim3(256), 0, stream, x, Wsw, bias, xW);
  hipLaunchKernelGGL(k_scan, dim3(256), dim3(256), 0, stream, U, xW, hbuf, bar, out);
}

// Round 2
// 3863.664 us; speedup vs baseline: 2.3479x; 2.3479x over previous
//
#include <hip/hip_runtime.h>
#include <cstdint>
#include <cstddef>

// CustomLSTM: B=64, S=512, I=1024, H=1024.
//   K1: convert W fp32 -> bf16, swizzled into MFMA-B-fragment order.
//   K2: xW = x@W + bias  (bf16 MFMA, 128x128 tiles), stored bf16 in scan layout.
//   K3: persistent scan: 256 wgs (4 batch-groups x 64 unit-groups), U held in
//       VGPRs as B-fragments. Cross-wg h exchange via *coherence-flagged*
//       (sc0/sc1, relaxed agent-scope atomic) loads/stores through the LLC —
//       NO __threadfence (round-1's 16us/step was buffer_wbl2/buffer_inv L2
//       maintenance). Per-wg monotonic flags replace the hot atomic counter.

typedef __attribute__((ext_vector_type(4))) float        f32x4;
typedef __attribute__((ext_vector_type(8))) short        s16x8;
typedef __attribute__((ext_vector_type(4))) unsigned int u32x4;
typedef unsigned long long u64;

#define S_LEN 512
#define HID   33554432   // 64*512*1024

__device__ __forceinline__ unsigned short f2bf(float f) {
  unsigned u = __builtin_bit_cast(unsigned, f);
  u += 0x7FFFu + ((u >> 16) & 1u);           // round-to-nearest-even
  return (unsigned short)(u >> 16);
}
__device__ __forceinline__ float bf2f(unsigned short h) {
  unsigned u = ((unsigned)h) << 16;
  return __builtin_bit_cast(float, u);
}
__device__ __forceinline__ float sigm(float x) {
  return __fdividef(1.f, 1.f + __expf(-x));
}
__device__ __forceinline__ float tanh_(float x) {
  return 1.f - __fdividef(2.f, 1.f + __expf(2.f * x));
}

// ---------------- K1: W fp32 -> bf16, B-fragment swizzle ----------------
// W_sw layout: [kb=K/32][nb=N/128][ksub=4][col=128][i=8]  (k = kb*32+ksub*8+i)
__global__ __launch_bounds__(256) void k_convW(const float* __restrict__ W,
                                               unsigned short* __restrict__ Wsw) {
  int idx = blockIdx.x * 256 + threadIdx.x;   // 0 .. 4194303
  int k = idx >> 12, c = idx & 4095;
  int kb = k >> 5, ksub = (k >> 3) & 3, i = k & 7;
  int nb = c >> 7, col = c & 127;
  Wsw[(size_t)(((kb * 32 + nb) * 4 + ksub) * 128 + col) * 8 + i] = f2bf(W[idx]);
}

// ---------------- K2: xW = x @ W + bias ----------------
// grid (nb=32, mb=256), 256 thr. Output layout: xW[g][s][b][j] bf16,
// offset = ((g*512+s)*64+b)*1024 + j   (g=gate 0..3, j=0..1023)
__global__ __launch_bounds__(256) void k_gemm(const float* __restrict__ x,
                                              const unsigned short* __restrict__ Wsw,
                                              const float* __restrict__ bias,
                                              unsigned short* __restrict__ xW) {
  __shared__ __align__(16) short As[4096];   // [ksub=4][row=128][8] bf16
  __shared__ __align__(16) short Bs[4096];   // [ksub=4][col=128][8] bf16
  const int nb = blockIdx.x;
  const int mb = blockIdx.y;
  const int tid = threadIdx.x;
  const int w = tid >> 6, lane = tid & 63;
  const int wm = w >> 1, wn = w & 1;
  const int quad = lane >> 4, l15 = lane & 15;

  f32x4 acc[4][4];
#pragma unroll
  for (int mt = 0; mt < 4; ++mt)
#pragma unroll
    for (int nt = 0; nt < 4; ++nt) acc[mt][nt] = (f32x4){0.f, 0.f, 0.f, 0.f};

  const int r = tid >> 1, half = tid & 1;
  const float* xrow = x + (size_t)(mb * 128 + r) * 1024 + half * 16;
  const u32x4* wsrc = (const u32x4*)Wsw;
  u32x4* bdst = (u32x4*)Bs;
  s16x8* asv = (s16x8*)As;

  for (int kb = 0; kb < 32; ++kb) {
    f32x4 v0 = *(const f32x4*)(xrow + kb * 32);
    f32x4 v1 = *(const f32x4*)(xrow + kb * 32 + 4);
    f32x4 v2 = *(const f32x4*)(xrow + kb * 32 + 8);
    f32x4 v3 = *(const f32x4*)(xrow + kb * 32 + 12);
    s16x8 s0, s1;
    s0[0] = (short)f2bf(v0[0]); s0[1] = (short)f2bf(v0[1]);
    s0[2] = (short)f2bf(v0[2]); s0[3] = (short)f2bf(v0[3]);
    s0[4] = (short)f2bf(v1[0]); s0[5] = (short)f2bf(v1[1]);
    s0[6] = (short)f2bf(v1[2]); s0[7] = (short)f2bf(v1[3]);
    s1[0] = (short)f2bf(v2[0]); s1[1] = (short)f2bf(v2[1]);
    s1[2] = (short)f2bf(v2[2]); s1[3] = (short)f2bf(v2[3]);
    s1[4] = (short)f2bf(v3[0]); s1[5] = (short)f2bf(v3[1]);
    s1[6] = (short)f2bf(v3[2]); s1[7] = (short)f2bf(v3[3]);
    asv[(half * 2 + 0) * 128 + r] = s0;
    asv[(half * 2 + 1) * 128 + r] = s1;
    const u32x4* bsrc = wsrc + (size_t)(kb * 32 + nb) * 512;
    bdst[tid] = bsrc[tid];
    bdst[tid + 256] = bsrc[tid + 256];
    __syncthreads();

    s16x8 a[4], b[4];
#pragma unroll
    for (int mt = 0; mt < 4; ++mt)
      a[mt] = ((const s16x8*)As)[quad * 128 + wm * 64 + mt * 16 + l15];
#pragma unroll
    for (int nt = 0; nt < 4; ++nt)
      b[nt] = ((const s16x8*)Bs)[quad * 128 + wn * 64 + nt * 16 + l15];
#pragma unroll
    for (int mt = 0; mt < 4; ++mt)
#pragma unroll
      for (int nt = 0; nt < 4; ++nt)
        acc[mt][nt] =
            __builtin_amdgcn_mfma_f32_16x16x32_bf16(a[mt], b[nt], acc[mt][nt], 0, 0, 0);
    __syncthreads();
  }

#pragma unroll
  for (int mt = 0; mt < 4; ++mt) {
    const int gr0 = mb * 128 + wm * 64 + mt * 16 + quad * 4;
#pragma unroll
    for (int nt = 0; nt < 4; ++nt) {
      const int gc = nb * 128 + wn * 64 + nt * 16 + l15;
      const int g = gc >> 10, jg = gc & 1023;
      const float bb = bias[gc];
#pragma unroll
      for (int r2 = 0; r2 < 4; ++r2) {
        const int gr = gr0 + r2;
        const int bi = gr >> 9, s = gr & 511;   // row = b*512 + s
        xW[(size_t)((g * 512 + s) * 64 + bi) * 1024 + jg] = f2bf(acc[mt][nt][r2] + bb);
      }
    }
  }
}

// ---------------- K3: persistent scan ----------------
// 256 wgs x 256 thr. wg: mi=wg>>6 (batch group of 16), ni=wg&63 (16 units).
// wave w = K-slice [w*256, w*256+256). U B-frags live in 128 VGPRs/lane.
// h_buf (global, bf16, double-buffered): [parity][mi][kb=32][lane=64][8],
// exactly A-fragment order so staging is a linear 32KB copy.
// Sync protocol (NO fences): all cross-wg data ops are relaxed agent-scope
// atomics (sc0/sc1 flagged -> write-through / read-from LLC). __syncthreads'
// vmcnt(0) drain orders each wg's data stores before its flag store.
// flag[wg] = t+1 at end of step t (after reading tile t-1) -- so a reader
// waiting flag >= t knows tile t-1 is fully written AND tile t-2 fully read
// (safe to overwrite with tile t).
__global__ __launch_bounds__(256, 1) void k_scan(const float* __restrict__ U,
                                                 const unsigned short* __restrict__ xW,
                                                 unsigned short* hbuf,
                                                 unsigned* flags,
                                                 float* __restrict__ out) {
  __shared__ __align__(16) short hA[16384];   // 32KB staged h tile
  __shared__ __align__(16) float P[5120];     // [w=4][g=4][j=16][b=20pad] partials

  const int wg = blockIdx.x;
  const int mi = wg >> 6, ni = wg & 63;
  const int tid = threadIdx.x;
  const int w = tid >> 6, lane = tid & 63;
  const int quad = lane >> 4, l15 = lane & 15;
  const int b_loc = tid >> 4, j_loc = tid & 15;

  // ---- load U fragments into registers (one-time) ----
  s16x8 uf[4][8];
  {
    const int cbase = ni * 16 + l15;
#pragma unroll
    for (int g = 0; g < 4; ++g) {
#pragma unroll
      for (int kb = 0; kb < 8; ++kb) {
        const int k0 = w * 256 + kb * 32 + quad * 8;
        s16x8 v;
#pragma unroll
        for (int i = 0; i < 8; ++i)
          v[i] = (short)f2bf(U[(size_t)(k0 + i) * 4096 + g * 1024 + cbase]);
        uf[g][kb] = v;
      }
    }
  }

  const int bg = mi * 16 + b_loc;             // global batch
  const int jg = ni * 16 + j_loc;             // global hidden unit
  const size_t hb_w_off =
      (size_t)((mi * 32 + (jg >> 5)) * 64 + ((jg >> 3) & 3) * 16 + b_loc) * 8 + (jg & 7);
  unsigned* myflag = flags + (size_t)(mi * 64 + ni) * 4;   // 16B stride
  float c = 0.f;
  const s16x8* hAv = (const s16x8*)hA;

  for (int t = 0; t < S_LEN; ++t) {
    // prefetch xW for this (t, b, j): 4 gates (xW immutable -> plain loads)
    unsigned short xwv[4];
#pragma unroll
    for (int g = 0; g < 4; ++g)
      xwv[g] = xW[(size_t)((g * 512 + t) * 64 + bg) * 1024 + jg];

    float gate[4];
    if (t > 0) {
      // wave 0: 64 threads each poll one wg's flag (parallel, no hot line)
      if (tid < 64) {
        const unsigned* fp = flags + (size_t)(mi * 64 + tid) * 4;
        while (__hip_atomic_load(fp, __ATOMIC_RELAXED, __HIP_MEMORY_SCOPE_AGENT) <
               (unsigned)t)
          __builtin_amdgcn_s_sleep(1);
      }
      __syncthreads();

      // stage h tile: 32KB of coherent (LLC) 8B loads, linear fragment order
      const u64* src = (const u64*)hbuf + (size_t)((t & 1) ^ 1) * 16384 + (size_t)mi * 4096;
      u64* dst = (u64*)hA;
#pragma unroll
      for (int c2 = 0; c2 < 16; ++c2)
        dst[c2 * 256 + tid] =
            __hip_atomic_load(src + c2 * 256 + tid, __ATOMIC_RELAXED,
                              __HIP_MEMORY_SCOPE_AGENT);
      __syncthreads();

      f32x4 acc[4];
#pragma unroll
      for (int g = 0; g < 4; ++g) acc[g] = (f32x4){0.f, 0.f, 0.f, 0.f};
#pragma unroll
      for (int kb = 0; kb < 8; ++kb) {
        s16x8 a = hAv[(w * 8 + kb) * 64 + lane];
#pragma unroll
        for (int g = 0; g < 4; ++g)
          acc[g] = __builtin_amdgcn_mfma_f32_16x16x32_bf16(a, uf[g][kb], acc[g], 0, 0, 0);
      }
#pragma unroll
      for (int g = 0; g < 4; ++g) {
        float* dp = &P[(((w * 4 + g) * 16) + l15) * 20 + quad * 4];
        *(f32x4*)dp = acc[g];
      }
      __syncthreads();
#pragma unroll
      for (int g = 0; g < 4; ++g) {
        float s = bf2f(xwv[g]);
#pragma unroll
        for (int w2 = 0; w2 < 4; ++w2)
          s += P[((w2 * 4 + g) * 16 + j_loc) * 20 + b_loc];
        gate[g] = s;
      }
    } else {
#pragma unroll
      for (int g = 0; g < 4; ++g) gate[g] = bf2f(xwv[g]);
    }

    const float it = sigm(gate[0]);
    const float ft = sigm(gate[1]);
    const float gt = tanh_(gate[2]);
    const float ot = sigm(gate[3]);
    c = ft * c + it * gt;
    const float h = ot * tanh_(c);

    // coherent h store first (critical path), then bulk out stores
    __hip_atomic_store(hbuf + (size_t)(t & 1) * 65536 + hb_w_off, f2bf(h),
                       __ATOMIC_RELAXED, __HIP_MEMORY_SCOPE_AGENT);
    out[(size_t)bg * (S_LEN * 1024) + (size_t)t * 1024 + jg] = h;
    if (t == S_LEN - 1) {
      out[HID + (size_t)bg * 1024 + jg] = h;                 // h_t
      out[HID + 65536 + (size_t)bg * 1024 + jg] = c;         // c_t
    }

    __syncthreads();   // vmcnt(0) drain for ALL waves before flag publish
    if (tid == 0)
      __hip_atomic_store(myflag, (unsigned)(t + 1), __ATOMIC_RELAXED,
                         __HIP_MEMORY_SCOPE_AGENT);
    __syncthreads();   // nobody races ahead to re-poll before publish
  }
}

// ---------------- launch ----------------
extern "C" void kernel_launch(void* const* d_in, const int* in_sizes, int n_in,
                              void* d_out, int out_size, void* d_ws, size_t ws_size,
                              hipStream_t stream) {
  const float* x = (const float*)d_in[0];     // [64,512,1024]
  const float* W = (const float*)d_in[1];     // [1024,4096]
  const float* U = (const float*)d_in[2];     // [1024,4096]
  const float* bias = (const float*)d_in[3];  // [4096]
  float* out = (float*)d_out;
  char* ws = (char*)d_ws;

  // ws layout:
  unsigned* flags = (unsigned*)ws;                                   // 4 KB
  unsigned short* hbuf = (unsigned short*)(ws + 4096);               // 256 KB
  unsigned short* Wsw = (unsigned short*)(ws + 4096 + 262144);       // 8 MB
  unsigned short* xW = (unsigned short*)(ws + 4096 + 262144 + 8388608);  // 256 MB

  hipMemsetAsync(ws, 0, 4096, stream);   // zero flags

  hipLaunchKernelGGL(k_convW, dim3(16384), dim3(256), 0, stream, W, Wsw);
  hipLaunchKernelGGL(k_gemm, dim3(32, 256), dim3(256), 0, stream, x, Wsw, bias, xW);
  hipLaunchKernelGGL(k_scan, dim3(256), dim3(256), 0, stream, U, xW, hbuf, flags, out);
}